// Round 7
// baseline (321.369 us; speedup 1.0000x reference)
//
#include <hip/hip_runtime.h>

#define HH   224
#define WW   224
#define HW_  (HH * WW)
#define TW   16               // tile width
#define TH   8                // tile height
#define HLW  18               // halo width
#define HLH  10               // halo height
#define XSR  184              // padded elements per channel row-plane (368 B)

typedef __attribute__((ext_vector_type(8))) short bf16x8;
typedef __attribute__((ext_vector_type(4))) short bf16x4;
typedef __attribute__((ext_vector_type(4))) float f32x4;

static __device__ __forceinline__ unsigned short f2bf(float f) {
    unsigned u = __float_as_uint(f);
    u += 0x7FFFu + ((u >> 16) & 1u);          // RNE
    return (unsigned short)(u >> 16);
}
static __device__ __forceinline__ float bf2f(unsigned short h) {
    return __uint_as_float(((unsigned)h) << 16);
}

// ---- pre-kernel: w1 -> bf16 [64][64]; w2 -> bf16 padded [64 ch][16 taps][64 o],
//      taps 9..15 zeroed so GEMM2 A-fragment loads are branchless ----
__global__ __launch_bounds__(256) void prep_weights(
    const float* __restrict__ w1, const float* __restrict__ w2,
    unsigned short* __restrict__ wsb)
{
    const int i = blockIdx.x * 256 + threadIdx.x;   // 0..65535
    unsigned short* w1b = wsb;                      // 4096 bf16
    unsigned short* w2p = wsb + 4096;               // 65536 bf16
    if (i < 4096) w1b[i] = f2bf(w1[i]);
    const int c  = i >> 10;
    const int rr = (i >> 6) & 15;
    const int o  = i & 63;
    float v = (rr < 9) ? w2[(c * 9 + rr) * 64 + o] : 0.f;
    w2p[i] = f2bf(v);
}

// LDS: channel-major xs only: 64 ch x 368B = 23,552 B -> 6 blocks/CU
__global__ __launch_bounds__(256, 6) void dynconv_mfma16(
    const float* __restrict__ x, const unsigned short* __restrict__ wsb,
    float* __restrict__ out)
{
    __shared__ __align__(16) unsigned short xs[64 * XSR];

    const unsigned char* w1b = (const unsigned char*)wsb;            // bf16 [64 o][64 c]
    const unsigned char* w2p = (const unsigned char*)(wsb + 4096);   // bf16 [64 ch][16 tap][64 o]

    const int b    = blockIdx.z;
    const int ty0  = blockIdx.y * TH;
    const int tx0  = blockIdx.x * TW;
    const int tid  = threadIdx.x;
    const int lane = tid & 63;
    const int w    = tid >> 6;      // wave 0..3 -> tile rows w*2, w*2+1
    const int tx   = lane & 15;
    const int g    = lane >> 4;

    const float* xb = x + (size_t)b * 64 * HW_;

    // ---- stage x halo tile (fp32 -> bf16), channel-major, x-pairs ----
    // per channel: 10 rows x 18 cols = 180 u16 (90 u32), row stride 18 elems
    for (int i = tid; i < 64 * 90; i += 256) {
        int c    = i / 90;
        int rem  = i - c * 90;
        int r    = rem / 9;
        int cp   = rem - r * 9;
        int col0 = cp * 2;
        int gy   = ty0 + r - 1;
        int gx0  = tx0 + col0 - 1;
        float f0 = 0.f, f1 = 0.f;
        if ((unsigned)gy < (unsigned)HH) {
            const float* rowp = xb + c * HW_ + gy * WW;
            if ((unsigned)gx0 < (unsigned)WW)       f0 = rowp[gx0];
            if ((unsigned)(gx0 + 1) < (unsigned)WW) f1 = rowp[gx0 + 1];
        }
        unsigned pk = (unsigned)f2bf(f0) | ((unsigned)f2bf(f1) << 16);
        *(unsigned*)((unsigned char*)xs + c * 368 + (r * HLW + col0) * 2) = pk;
    }
    __syncthreads();

    // ---- GEMM1: h = relu(w1 . x) via 16x16x32; outputs packed directly into
    //      GEMM2 B-fragments bq[q][kb] (16x16x16 B layout k=4g+j == C/D row=4g+r) ----
    bf16x4 bq[2][4];
    {
        bf16x8 aw1[4][2];
        #pragma unroll
        for (int mt = 0; mt < 4; ++mt)
            #pragma unroll
            for (int kt = 0; kt < 2; ++kt)
                aw1[mt][kt] = *(const bf16x8*)(w1b + (mt * 16 + tx) * 128 + kt * 64 + g * 16);
        #pragma unroll
        for (int q = 0; q < 2; ++q) {
            const int center = (w * 2 + q + 1) * HLW + (tx + 1);
            bf16x8 bx[2];
            #pragma unroll
            for (int kt = 0; kt < 2; ++kt) {
                bf16x8 t;
                #pragma unroll
                for (int j = 0; j < 8; ++j)
                    t[j] = (short)xs[(kt * 32 + g * 8 + j) * XSR + center];
                bx[kt] = t;
            }
            #pragma unroll
            for (int mt = 0; mt < 4; ++mt) {
                f32x4 hc = {0.f, 0.f, 0.f, 0.f};
                hc = __builtin_amdgcn_mfma_f32_16x16x32_bf16(aw1[mt][0], bx[0], hc, 0, 0, 0);
                hc = __builtin_amdgcn_mfma_f32_16x16x32_bf16(aw1[mt][1], bx[1], hc, 0, 0, 0);
                unsigned lo = (unsigned)f2bf(fmaxf(hc[0], 0.f)) | ((unsigned)f2bf(fmaxf(hc[1], 0.f)) << 16);
                unsigned hi = (unsigned)f2bf(fmaxf(hc[2], 0.f)) | ((unsigned)f2bf(fmaxf(hc[3], 0.f)) << 16);
                union { uint2 u; bf16x4 v; } cv;
                cv.u = make_uint2(lo, hi);
                bq[q][mt] = cv.v;    // h[o = mt*16 + 4g + j][pix(q,tx)]
            }
        }
    }

    // ---- patch pixel offsets per (q, r): tap k = g*4+r (taps >=9 have zero kern) ----
    int poff[2][4];
    #pragma unroll
    for (int q = 0; q < 2; ++q)
        #pragma unroll
        for (int r = 0; r < 4; ++r) {
            int kk = g * 4 + r;
            int kv = kk < 9 ? kk : 0;
            int dy = kv / 3;
            int dx = kv - dy * 3;
            poff[q][r] = (w * 2 + q + dy) * HLW + (tx + dx);
        }

    const int orow = ty0 + w * 2 + g;                    // valid for g < 2
    float* outp = out + (size_t)b * 64 * HW_ + (size_t)orow * WW + tx0 + tx;

    // ---- GEMM2 (16x16x16, A=w2 from L2, B=bq regs) + tap contract ----
    const unsigned char* w2l = w2p + tx * 128 + g * 8;   // + c*2048 + kb*32
    uint2 pf[4];
    #pragma unroll
    for (int kb = 0; kb < 4; ++kb) pf[kb] = *(const uint2*)(w2l + kb * 32);

    for (int c = 0; c < 64; ++c) {
        union { uint2 u; bf16x4 v; } a2[4];
        #pragma unroll
        for (int kb = 0; kb < 4; ++kb) a2[kb].u = pf[kb];
        const int cn = (c < 63) ? c + 1 : 63;
        #pragma unroll
        for (int kb = 0; kb < 4; ++kb) pf[kb] = *(const uint2*)(w2l + cn * 2048 + kb * 32);

        f32x4 acc0 = {0.f, 0.f, 0.f, 0.f};
        f32x4 acc1 = {0.f, 0.f, 0.f, 0.f};
        #pragma unroll
        for (int kb = 0; kb < 4; ++kb) {
            acc0 = __builtin_amdgcn_mfma_f32_16x16x16bf16_1k(a2[kb].v, bq[0][kb], acc0, 0, 0, 0);
            acc1 = __builtin_amdgcn_mfma_f32_16x16x16bf16_1k(a2[kb].v, bq[1][kb], acc1, 0, 0, 0);
        }

        const unsigned short* xc = xs + c * XSR;
        float s0 = 0.f, s1 = 0.f;
        #pragma unroll
        for (int r = 0; r < 4; ++r) {
            s0 = fmaf(acc0[r], bf2f(xc[poff[0][r]]), s0);
            s1 = fmaf(acc1[r], bf2f(xc[poff[1][r]]), s1);
        }
        s0 += __shfl_xor(s0, 16, 64); s0 += __shfl_xor(s0, 32, 64);
        s1 += __shfl_xor(s1, 16, 64); s1 += __shfl_xor(s1, 32, 64);

        if (g < 2) {
            float v = (g == 0) ? s0 : s1;
            outp[(size_t)c * HW_] = v;   // 32 lanes = 2 rows x 64B, coalesced
        }
    }
}

extern "C" void kernel_launch(void* const* d_in, const int* in_sizes, int n_in,
                              void* d_out, int out_size, void* d_ws, size_t ws_size,
                              hipStream_t stream) {
    (void)in_sizes; (void)n_in; (void)out_size; (void)ws_size;
    const float* x  = (const float*)d_in[0];
    const float* w1 = (const float*)d_in[1];
    const float* w2 = (const float*)d_in[2];
    float* out = (float*)d_out;
    unsigned short* wsb = (unsigned short*)d_ws;    // 139,264 bytes used

    prep_weights<<<256, 256, 0, stream>>>(w1, w2, wsb);

    dim3 grid(WW / TW, HH / TH, 4);   // 14 x 28 x 4 = 1568 blocks
    dynconv_mfma16<<<grid, 256, 0, stream>>>(x, wsb, out);
}